// Round 15
// baseline (308.175 us; speedup 1.0000x reference)
//
#include <hip/hip_runtime.h>
#include <hip/hip_bf16.h>

// MSCN fused pipeline, MI355X gfx950. Round 14: LN folded into kv GEMM
// (stats-only LN pass; gamma folded into WkvT; affine fix-up in kv epilogue;
// yln buffer eliminated).
// B=64, C=512, H=W=7 (N=49), HY=WY=28 (N1=784), heads=8, d=64, SCALE=0.125
// kc1 = 784//2 = 392, kc2 = 784//3 = 261

typedef __hip_bfloat16 bf16;
using bf16x8 = __attribute__((ext_vector_type(8))) short;  // 8 bf16 = 4 VGPRs
using f32x4 = __attribute__((ext_vector_type(4))) float;

#define DI __device__ __forceinline__

DI unsigned short b2u(float f) {
  bf16 h = __float2bfloat16(f);
  return *reinterpret_cast<unsigned short*>(&h);
}
DI float u2f(short s) { return __uint_as_float(((unsigned int)(unsigned short)s) << 16); }

// inverse of the monotone float->uint key map (key = sign? ~u : u|0x80000000)
DI float unkey(unsigned int k) {
  unsigned int u = (k & 0x80000000u) ? (k & 0x7FFFFFFFu) : ~k;
  return __uint_as_float(u);
}

#define GLD_LDS16(g, l)                                                              \
  __builtin_amdgcn_global_load_lds((const __attribute__((address_space(1))) unsigned int*)(g), \
                                   (__attribute__((address_space(3))) unsigned int*)(l), 16, 0, 0)

// ---------------------------------------------------------------- prep + pool (merged)
// blocks [0,512): WkvT*gamma; [512,768): WqT; [768,1024): WprojT;
// [1024,1536): xstT (LDS-tiled); [1536,3584): vtpad; [3584,7680): pool
// (XCD-swizzled, wave-parallel scan); [7680,7712): c1/c2 reductions.
__global__ __launch_bounds__(256) void prep_pool_kernel(
    const float* __restrict__ Wkv, const float* __restrict__ Wq, const float* __restrict__ Wproj,
    const float* __restrict__ x, const float* __restrict__ y, const float* __restrict__ gamma,
    const float* __restrict__ beta, bf16* __restrict__ wkvT, bf16* __restrict__ wqT,
    bf16* __restrict__ wpT, bf16* __restrict__ xsTb, bf16* __restrict__ Vt,
    bf16* __restrict__ pooledT, float* __restrict__ c1, float* __restrict__ c2) {
  __shared__ __align__(16) unsigned char pMem[26912];  // union: t/xt/I/red
  const int blk = blockIdx.x;
  const int tid = threadIdx.x;
  if (blk < 1024) {
    float(*t)[33] = reinterpret_cast<float(*)[33]>(pMem);
    const float* W;
    bf16* WT;
    int N, bx, by;
    bool foldg = false;
    if (blk < 512) { W = Wkv; WT = wkvT; N = 1024; bx = blk & 31; by = blk >> 5; foldg = true; }
    else if (blk < 768) { W = Wq; WT = wqT; N = 512; bx = (blk - 512) & 15; by = (blk - 512) >> 4; }
    else { W = Wproj; WT = wpT; N = 512; bx = (blk - 768) & 15; by = (blk - 768) >> 4; }
    const int n0 = bx * 32, k0 = by * 32;
    for (int i = tid; i < 1024; i += 256) {
      int kr = i >> 5, nc = i & 31;
      t[kr][nc] = W[(size_t)(k0 + kr) * N + n0 + nc];
    }
    __syncthreads();
    for (int i = tid; i < 1024; i += 256) {
      int nr = i >> 5, kc = i & 31;
      float v = t[kc][nr];
      if (foldg) v *= gamma[k0 + kc];
      WT[(size_t)(n0 + nr) * 512 + k0 + kc] = __float2bfloat16(v);
    }
  } else if (blk < 1536) {
    // xstT: block = (b, 64-c-group). Contiguous read, LDS transpose, coalesced write.
    float(*xt)[51] = reinterpret_cast<float(*)[51]>(pMem);  // [64][51] f32
    const int q2 = blk - 1024;
    const int b = q2 >> 3, cg = q2 & 7;
    const float* xp = x + ((size_t)b * 512 + cg * 64) * 49;
    for (int i = tid; i < 3136; i += 256) {
      int cc = i / 49, r = i - cc * 49;
      xt[cc][r] = xp[i];
    }
    __syncthreads();
    for (int i = tid; i < 3136; i += 256) {
      int r = i >> 6, cc = i & 63;
      xsTb[((size_t)b * 49 + r) * 512 + cg * 64 + cc] = __float2bfloat16(xt[cc][r]);
    }
  } else if (blk < 3584) {
    int idx = (blk - 1536) * 256 + tid;  // 524288 total
    int row = idx >> 4, c = idx & 15;
    Vt[(size_t)row * 800 + 784 + c] = __float2bfloat16(0.f);
  } else if (blk < 7680) {
    // pool: wave-parallel 2D prefix scan; XCD swizzle keeps one b per XCD.
    float(*I)[841] = reinterpret_cast<float(*)[841]>(pMem);  // [plane][29*29]
    const int p = blk - 3584;  // [0,4096)
    const int wk = (p & 7) * 512 + (p >> 3);
    const int b = wk >> 6, cg = wk & 63;
    const float* srcb = y + ((size_t)b * 512 + cg * 8) * 784;
    bf16* drow = pooledT + ((size_t)b * 784) * 512 + cg * 8;
    for (int i = tid; i < 8 * 57; i += 256) {
      int q = i / 57, e = i - q * 57;
      I[q][(e < 29) ? e : (e - 28) * 29] = 0.f;
    }
    {
      const int w = tid >> 6, lane = tid & 63;
      const int hl = lane >> 5, c = lane & 31;
      const int pp = w * 2 + hl;
      if (c < 28) {
        const float* sp = srcb + (size_t)pp * 784;
        float run = 0.f;
        for (int r = 0; r < 28; ++r) {
          float v = sp[r * 28 + c];
#pragma unroll
          for (int d = 1; d < 28; d <<= 1) {
            float tt = __shfl_up(v, d, 32);
            if (c >= d) v += tt;
          }
          run += v;
          I[pp][(r + 1) * 29 + c + 1] = run;
        }
      }
    }
    __syncthreads();
    for (int j = tid; j < 784; j += 256) {
      int r = j / 28, c = j - (j / 28) * 28;
      int r0[3], r1[3], c0[3], c1i[3];
#pragma unroll
      for (int pk = 1; pk <= 3; ++pk) {
        r0[pk - 1] = max(r - pk, 0) * 29;
        r1[pk - 1] = (min(r + pk, 27) + 1) * 29;
        c0[pk - 1] = max(c - pk, 0);
        c1i[pk - 1] = min(c + pk, 27) + 1;
      }
      unsigned int u[4];
#pragma unroll
      for (int q = 0; q < 4; ++q) {
        float vv[2];
#pragma unroll
        for (int tt = 0; tt < 2; ++tt) {
          const float* Ip = I[q * 2 + tt];
          float acc = 0.f;
#pragma unroll
          for (int k = 0; k < 3; ++k) {
            float s = Ip[r1[k] + c1i[k]] - Ip[r0[k] + c1i[k]] - Ip[r1[k] + c0[k]] + Ip[r0[k] + c0[k]];
            acc += s * ((k == 0) ? (1.f / 9.f) : (k == 1) ? (1.f / 25.f) : (1.f / 49.f));
          }
          vv[tt] = acc;
        }
        u[q] = (unsigned int)b2u(vv[0]) | ((unsigned int)b2u(vv[1]) << 16);
      }
      *reinterpret_cast<uint4*>(drow + (size_t)j * 512) = make_uint4(u[0], u[1], u[2], u[3]);
    }
  } else {
    // c1[n] = sum_k gamma[k]*Wkv[k][n]; c2[n] = sum_k beta[k]*Wkv[k][n]
    float* red = reinterpret_cast<float*>(pMem);  // [2][8][32]
    const int n0c = (blk - 7680) * 32;
    const int kk = tid >> 5, c = tid & 31;
    float p1 = 0.f, p2 = 0.f;
    for (int k = kk; k < 512; k += 8) {
      float wv = Wkv[(size_t)k * 1024 + n0c + c];
      p1 += gamma[k] * wv;
      p2 += beta[k] * wv;
    }
    red[kk * 32 + c] = p1;
    red[256 + kk * 32 + c] = p2;
    __syncthreads();
    if (tid < 32) {
      float s1 = 0.f, s2v = 0.f;
#pragma unroll
      for (int q = 0; q < 8; ++q) {
        s1 += red[q * 32 + tid];
        s2v += red[256 + q * 32 + tid];
      }
      c1[n0c + tid] = s1;
      c2[n0c + tid] = s2v;
    }
  }
}

// ---------------------------------------------------------------- stats + q_mfma (merged)
// blocks [0,100): q_mfma; [100,12644): LN row stats (mu, rs) only.
__global__ __launch_bounds__(256) void stats_q_kernel(const bf16* __restrict__ pooledT,
                                                      float2* __restrict__ stats,
                                                      const bf16* __restrict__ A,
                                                      const bf16* __restrict__ Bt,
                                                      bf16* __restrict__ Qb) {
  __shared__ __align__(16) bf16 As[128 * 32];
  __shared__ __align__(16) bf16 Bs[128 * 32];
  const int blk = blockIdx.x;
  const int tid = threadIdx.x;
  if (blk < 100) {
    const int lane = tid & 63;
    const int w = tid >> 6, wr = w >> 1, wc = w & 1;
    const int m0 = (blk >> 2) * 128, n0 = (blk & 3) * 128;
    f32x4 acc[4][4];
#pragma unroll
    for (int m = 0; m < 4; ++m)
#pragma unroll
      for (int n = 0; n < 4; ++n) acc[m][n] = f32x4{0.f, 0.f, 0.f, 0.f};
    const int s0 = tid, s1 = tid + 256;
    const bf16* Ag0 = A + (size_t)(m0 + (s0 >> 2)) * 512 + (s0 & 3) * 8;
    const bf16* Ag1 = A + (size_t)(m0 + (s1 >> 2)) * 512 + (s1 & 3) * 8;
    const bf16* Bg0 = Bt + (size_t)(n0 + (s0 >> 2)) * 512 + (s0 & 3) * 8;
    const bf16* Bg1 = Bt + (size_t)(n0 + (s1 >> 2)) * 512 + (s1 & 3) * 8;
    bf16* Al0 = As + s0 * 8;
    bf16* Al1 = As + s1 * 8;
    bf16* Bl0 = Bs + s0 * 8;
    bf16* Bl1 = Bs + s1 * 8;
    const int fr = lane & 15;
    const int ko = (lane >> 4) * 8;
    const int rh = lane >> 4;
    for (int k0 = 0; k0 < 512; k0 += 32) {
      GLD_LDS16(Ag0 + k0, Al0);
      GLD_LDS16(Ag1 + k0, Al1);
      GLD_LDS16(Bg0 + k0, Bl0);
      GLD_LDS16(Bg1 + k0, Bl1);
      __syncthreads();
      bf16x8 af[4], bfr[4];
#pragma unroll
      for (int m = 0; m < 4; ++m)
        af[m] = *reinterpret_cast<const bf16x8*>(As + (wr * 64 + m * 16 + fr) * 32 + ko);
#pragma unroll
      for (int n = 0; n < 4; ++n)
        bfr[n] = *reinterpret_cast<const bf16x8*>(Bs + (wc * 64 + n * 16 + fr) * 32 + ko);
#pragma unroll
      for (int m = 0; m < 4; ++m)
#pragma unroll
        for (int n = 0; n < 4; ++n)
          acc[m][n] = __builtin_amdgcn_mfma_f32_16x16x32_bf16(af[m], bfr[n], acc[m][n], 0, 0, 0);
      __syncthreads();
    }
#pragma unroll
    for (int m = 0; m < 4; ++m) {
#pragma unroll
      for (int n = 0; n < 4; ++n) {
        int col = n0 + wc * 64 + n * 16 + fr;  // 0..511: h=col>>6, d=col&63
        const size_t cbase = ((size_t)(col >> 6)) * (49 * 64) + (col & 63);
#pragma unroll
        for (int r = 0; r < 4; ++r) {
          int row = m0 + wr * 64 + m * 16 + rh * 4 + r;
          if (row < 3136) {
            int b = row / 49, rr = row - (row / 49) * 49;
            Qb[((size_t)b * 8) * (49 * 64) + cbase + (size_t)rr * 64] = __float2bfloat16(acc[m][n][r]);
          }
        }
      }
    }
  } else {
    const int row = (blk - 100) * 4 + (tid >> 6);
    const int lane = tid & 63;
    bf16x8 raw = *reinterpret_cast<const bf16x8*>(pooledT + (size_t)row * 512 + lane * 8);
    float s = 0.f, s2 = 0.f;
#pragma unroll
    for (int j = 0; j < 8; ++j) {
      float v = u2f(raw[j]);
      s += v;
      s2 += v * v;
    }
#pragma unroll
    for (int off = 32; off; off >>= 1) {
      s += __shfl_xor(s, off, 64);
      s2 += __shfl_xor(s2, off, 64);
    }
    if (lane == 0) {
      float mu = s * (1.f / 512.f);
      float rs = rsqrtf(s2 * (1.f / 512.f) - mu * mu + 1e-5f);
      stats[row] = make_float2(mu, rs);
    }
  }
}

// ---------------------------------------------------------------- kv MFMA GEMM (LN-folded)
// A = pooledT bf16 [50176][512], Bt = (gamma-folded) WkvT bf16 [1024][512].
// Epilogue: v = rs_r*(acc - mu_r*c1[n]) + c2[n]; then K/V writes as before.
__global__ __launch_bounds__(256) void kv_mfma(const bf16* __restrict__ A,
                                               const bf16* __restrict__ Bt,
                                               const float2* __restrict__ stats,
                                               const float* __restrict__ c1,
                                               const float* __restrict__ c2,
                                               bf16* __restrict__ Kb, bf16* __restrict__ Vt) {
  extern __shared__ __align__(16) bf16 smem[];  // 18432 B dynamic
  bf16* As = smem;                              // [128*32]
  bf16* Bs = smem + 128 * 32;                   // [128*32]
  const int tid = threadIdx.x;
  const int lane = tid & 63;
  const int w = tid >> 6, wr = w >> 1, wc = w & 1;

  // XCD swizzle: XCD c handles y-tiles [c*49, c*49+49), all 8 x-tiles
  const int lin = blockIdx.y * 8 + blockIdx.x;
  const int c8 = lin & 7, j = lin >> 3;
  const int ex = j & 7, ey = c8 * 49 + (j >> 3);
  const int m0 = ey * 128, n0 = ex * 128;

  f32x4 acc[4][4];
#pragma unroll
  for (int m = 0; m < 4; ++m)
#pragma unroll
    for (int n = 0; n < 4; ++n) acc[m][n] = f32x4{0.f, 0.f, 0.f, 0.f};

  const int s0 = tid, s1 = tid + 256;
  const bf16* Ag0 = A + (size_t)(m0 + (s0 >> 2)) * 512 + (s0 & 3) * 8;
  const bf16* Ag1 = A + (size_t)(m0 + (s1 >> 2)) * 512 + (s1 & 3) * 8;
  const bf16* Bg0 = Bt + (size_t)(n0 + (s0 >> 2)) * 512 + (s0 & 3) * 8;
  const bf16* Bg1 = Bt + (size_t)(n0 + (s1 >> 2)) * 512 + (s1 & 3) * 8;
  bf16* Al0 = As + s0 * 8;
  bf16* Al1 = As + s1 * 8;
  bf16* Bl0 = Bs + s0 * 8;
  bf16* Bl1 = Bs + s1 * 8;

  const int fr = lane & 15;
  const int ko = (lane >> 4) * 8;
  const int rh = lane >> 4;

  for (int k0 = 0; k0 < 512; k0 += 32) {
    GLD_LDS16(Ag0 + k0, Al0);
    GLD_LDS16(Ag1 + k0, Al1);
    GLD_LDS16(Bg0 + k0, Bl0);
    GLD_LDS16(Bg1 + k0, Bl1);
    __syncthreads();
    bf16x8 af[4], bfr[4];
#pragma unroll
    for (int m = 0; m < 4; ++m)
      af[m] = *reinterpret_cast<const bf16x8*>(As + (wr * 64 + m * 16 + fr) * 32 + ko);
#pragma unroll
    for (int n = 0; n < 4; ++n)
      bfr[n] = *reinterpret_cast<const bf16x8*>(Bs + (wc * 64 + n * 16 + fr) * 32 + ko);
#pragma unroll
    for (int m = 0; m < 4; ++m)
#pragma unroll
      for (int n = 0; n < 4; ++n)
        acc[m][n] = __builtin_amdgcn_mfma_f32_16x16x32_bf16(af[m], bfr[n], acc[m][n], 0, 0, 0);
    __syncthreads();
  }

  // ---- LN affine fix-up: acc = rs*(acc - mu*c1[col]) + c2[col]
  {
    float muv[4][4], rsv[4][4];
#pragma unroll
    for (int m = 0; m < 4; ++m)
#pragma unroll
      for (int r = 0; r < 4; ++r) {
        int row = m0 + wr * 64 + m * 16 + rh * 4 + r;
        float2 st = stats[row];
        muv[m][r] = st.x;
        rsv[m][r] = st.y;
      }
    float c1v[4], c2v[4];
#pragma unroll
    for (int n = 0; n < 4; ++n) {
      int col = n0 + wc * 64 + n * 16 + fr;
      c1v[n] = c1[col];
      c2v[n] = c2[col];
    }
#pragma unroll
    for (int m = 0; m < 4; ++m)
#pragma unroll
      for (int n = 0; n < 4; ++n)
#pragma unroll
        for (int r = 0; r < 4; ++r)
          acc[m][n][r] = rsv[m][r] * (acc[m][n][r] - muv[m][r] * c1v[n]) + c2v[n];
  }

  if (n0 < 512) {
    // ---- K epilogue
#pragma unroll
    for (int m = 0; m < 4; ++m) {
#pragma unroll
      for (int n = 0; n < 4; ++n) {
        int col = n0 + wc * 64 + n * 16 + fr;
        const size_t cbase = ((size_t)(col >> 6)) * (784 * 64) + (col & 63);
#pragma unroll
        for (int r = 0; r < 4; ++r) {
          int row = m0 + wr * 64 + m * 16 + rh * 4 + r;
          int b = row / 784, n1 = row - (row / 784) * 784;
          Kb[((size_t)b * 8) * (784 * 64) + cbase + (size_t)n1 * 64] = __float2bfloat16(acc[m][n][r]);
        }
      }
    }
  } else {
    // ---- V epilogue: LDS-staged transpose -> Vt [b*8+h][d][800]
    bf16* stage = smem;  // [128 cols][72 rows-padded]
#pragma unroll
    for (int p = 0; p < 2; ++p) {
      __syncthreads();
      if (wr == p) {
#pragma unroll
        for (int m = 0; m < 4; ++m) {
#pragma unroll
          for (int n = 0; n < 4; ++n) {
            int coll = wc * 64 + n * 16 + fr;
            int rowl = m * 16 + rh * 4;
            unsigned int u0 = (unsigned int)b2u(acc[m][n][0]) | ((unsigned int)b2u(acc[m][n][1]) << 16);
            unsigned int u1 = (unsigned int)b2u(acc[m][n][2]) | ((unsigned int)b2u(acc[m][n][3]) << 16);
            *reinterpret_cast<uint2*>(stage + coll * 72 + rowl) = make_uint2(u0, u1);
          }
        }
      }
      __syncthreads();
      const int rbase = m0 + p * 64;
      for (int i = tid; i < 1024; i += 256) {
        int cc = i >> 3, tc = i & 7;
        int colg = n0 + cc;  // >= 512
        int h = (colg >> 6) & 7, d = colg & 63;
        int rs = rbase + tc * 8;
        int b = rs / 784, n1 = rs - b * 784;
        bf16x8 val = *reinterpret_cast<const bf16x8*>(stage + cc * 72 + tc * 8);
        bf16* dst = Vt + (((size_t)b * 8 + h) * 64 + d) * 800 + n1;
        if (n1 <= 776) {
          *reinterpret_cast<bf16x8*>(dst) = val;
        } else {
#pragma unroll
          for (int jj = 0; jj < 8; ++jj) {
            int rr = rs + jj;
            int bb2 = rr / 784, nn1 = rr - bb2 * 784;
            bf16 hv;
            *reinterpret_cast<short*>(&hv) = val[jj];
            Vt[(((size_t)bb2 * 8 + h) * 64 + d) * 800 + nn1] = hv;
          }
        }
      }
    }
  }
}

// ---------------------------------------------------------------- proj MFMA GEMM
__global__ __launch_bounds__(256) void proj_mfma(const bf16* __restrict__ A,
                                                 const bf16* __restrict__ Bt,
                                                 const float* __restrict__ bias,
                                                 float* __restrict__ out) {
  __shared__ __align__(16) bf16 As[128 * 32];
  __shared__ __align__(16) bf16 Bs[128 * 32];
  const int tid = threadIdx.x;
  const int lane = tid & 63;
  const int w = tid >> 6, wr = w >> 1, wc = w & 1;
  const int m0 = blockIdx.y * 128, n0 = blockIdx.x * 128;

  f32x4 acc[4][4];
#pragma unroll
  for (int m = 0; m < 4; ++m)
#pragma unroll
    for (int n = 0; n < 4; ++n) acc[m][n] = f32x4{0.f, 0.f, 0.f, 0.f};

  const int s0 = tid, s1 = tid + 256;
  const bf16* Ag0 = A + (size_t)(m0 + (s0 >> 2)) * 1024 + (s0 & 3) * 8;
  const bf16* Ag1 = A + (size_t)(m0 + (s1 >> 2)) * 1024 + (s1 & 3) * 8;
  const bf16* Bg0 = Bt + (size_t)(n0 + (s0 >> 2)) * 512 + (s0 & 3) * 8;
  const bf16* Bg1 = Bt + (size_t)(n0 + (s1 >> 2)) * 512 + (s1 & 3) * 8;
  bf16* Al0 = As + s0 * 8;
  bf16* Al1 = As + s1 * 8;
  bf16* Bl0 = Bs + s0 * 8;
  bf16* Bl1 = Bs + s1 * 8;

  const int fr = lane & 15;
  const int ko = (lane >> 4) * 8;
  const int rh = lane >> 4;

  for (int k0 = 0; k0 < 1024; k0 += 32) {
    GLD_LDS16(Ag0 + k0, Al0);
    GLD_LDS16(Ag1 + k0, Al1);
    GLD_LDS16(Bg0 + (k0 & 511), Bl0);
    GLD_LDS16(Bg1 + (k0 & 511), Bl1);
    __syncthreads();
    bf16x8 af[4], bfr[4];
#pragma unroll
    for (int m = 0; m < 4; ++m)
      af[m] = *reinterpret_cast<const bf16x8*>(As + (wr * 64 + m * 16 + fr) * 32 + ko);
#pragma unroll
    for (int n = 0; n < 4; ++n)
      bfr[n] = *reinterpret_cast<const bf16x8*>(Bs + (wc * 64 + n * 16 + fr) * 32 + ko);
#pragma unroll
    for (int m = 0; m < 4; ++m)
#pragma unroll
      for (int n = 0; n < 4; ++n)
        acc[m][n] = __builtin_amdgcn_mfma_f32_16x16x32_bf16(af[m], bfr[n], acc[m][n], 0, 0, 0);
    __syncthreads();
  }

#pragma unroll
  for (int m = 0; m < 4; ++m) {
#pragma unroll
    for (int n = 0; n < 4; ++n) {
      int col = n0 + wc * 64 + n * 16 + fr;
      float bv = bias[col];
#pragma unroll
      for (int r = 0; r < 4; ++r) {
        int row = m0 + wr * 64 + m * 16 + rh * 4 + r;
        if (row < 3136) {
          int b = row / 49, rr = row - (row / 49) * 49;
          out[((size_t)b * 512 + col) * 49 + rr] = acc[m][n][r] + bv;
        }
      }
    }
  }
}

// ---------------------------------------------------------------- attention
// one block = (b,h, chunk of 7 q-rows). MFMA QK^T + MFMA PV with register
// load queues; 4 independent bisection chains; sW aliases sLog (stride 786).
__global__ __launch_bounds__(256, 7) void attn_kernel(const bf16* __restrict__ Qb,
                                                      const bf16* __restrict__ K,
                                                      const bf16* __restrict__ Vt,
                                                      const float* __restrict__ aw1p,
                                                      const float* __restrict__ aw2p,
                                                      bf16* __restrict__ aoutHL) {
  // XCD swizzle: 3584 = 8*448
  const int lin = blockIdx.x;
  const int wk = (lin & 7) * 448 + (lin >> 3);
  const int bh = wk / 7;
  const int chunk = wk - bh * 7;
  const int b = bh >> 3, h = bh & 7;
  const int r0 = chunk * 7;
  const int tid = threadIdx.x;
  const int lane = tid & 63, w = tid >> 6;
  __shared__ __align__(16) unsigned char sMem[22008];  // union: sLog f32[7][786] / sW bf16[8][808]
  float* sLog = reinterpret_cast<float*>(sMem);
  bf16* sW = reinterpret_cast<bf16*>(sMem);

  const int fr = lane & 15, ko = (lane >> 4) * 8, rh = lane >> 4;

  // ---- Q fragment: direct global load, row clamped (rows 7..15 garbage-OK)
  const bf16* Qp = Qb + ((size_t)bh * 49 + r0) * 64;
  const int qrow = (fr < 7) ? fr : 6;
  const bf16x8 aq0 = *reinterpret_cast<const bf16x8*>(Qp + qrow * 64 + ko);
  const bf16x8 aq1 = *reinterpret_cast<const bf16x8*>(Qp + qrow * 64 + 32 + ko);

  // ---- QK^T via MFMA with a 4-deep K register queue
  const bf16* Kp = K + (size_t)bh * (784 * 64);
  {
    const int rbase = rh * 4;
    const bf16* kbase = Kp + (size_t)fr * 64 + ko;
    bf16x8 kq0[4], kq1[4];
#pragma unroll
    for (int s = 0; s < 4; ++s) {
      int nt = w + s * 4;
      int ntc = nt < 49 ? nt : 48;
      const bf16* kr = kbase + (size_t)ntc * 1024;
      kq0[s] = *reinterpret_cast<const bf16x8*>(kr);
      kq1[s] = *reinterpret_cast<const bf16x8*>(kr + 32);
    }
#pragma unroll
    for (int i = 0; i < 13; ++i) {
      const int s = i & 3;
      const int nt = w + i * 4;
      if (nt < 49) {
        f32x4 acc = {0.f, 0.f, 0.f, 0.f};
        acc = __builtin_amdgcn_mfma_f32_16x16x32_bf16(aq0, kq0[s], acc, 0, 0, 0);
        acc = __builtin_amdgcn_mfma_f32_16x16x32_bf16(aq1, kq1[s], acc, 0, 0, 0);
#pragma unroll
        for (int r = 0; r < 4; ++r) {
          int row = rbase + r;
          if (row < 7) sLog[row * 786 + nt * 16 + fr] = acc[r] * 0.125f;
        }
      }
      const int ntn = w + (i + 4) * 4;
      if (ntn < 49) {
        const bf16* kr = kbase + (size_t)ntn * 1024;
        kq0[s] = *reinterpret_cast<const bf16x8*>(kr);
        kq1[s] = *reinterpret_cast<const bf16x8*>(kr + 32);
      }
    }
  }
  __syncthreads();

  // ---- load logits for this wave's two rows into registers
  const int ra = w;
  const int rb = (w + 4 < 7) ? (w + 4) : w;
  float va[13], vb[13];
#pragma unroll
  for (int i = 0; i < 13; ++i) {
    int m = lane + i * 64;
    va[i] = (m < 784) ? sLog[ra * 786 + m] : -INFINITY;
    vb[i] = (m < 784) ? sLog[rb * 786 + m] : -INFINITY;
  }
  __syncthreads();

  // row max
  float mxa = va[0], mxb = vb[0];
#pragma unroll
  for (int i = 1; i < 13; ++i) {
    mxa = fmaxf(mxa, va[i]);
    mxb = fmaxf(mxb, vb[i]);
  }
#pragma unroll
  for (int off = 32; off; off >>= 1) {
    mxa = fmaxf(mxa, __shfl_xor(mxa, off, 64));
    mxb = fmaxf(mxb, __shfl_xor(mxb, off, 64));
  }

  // ---- 4 independent bisection chains (exact; early exit on count==k)
  unsigned int t1a = 0u, t2a = 0u, t1b = 0u, t2b = 0u;
  bool d1a = false, d2a = false, d1b = false, d2b = false;
  for (int bit = 31; bit >= 0; --bit) {
    const unsigned int mb = 1u << bit;
    if (!d1a) {
      float cf = unkey(t1a | mb);
      int n = 0;
#pragma unroll
      for (int i = 0; i < 13; ++i) n += __popcll(__ballot(va[i] >= cf));
      if (n >= 392) { t1a |= mb; d1a = (n == 392); }
    }
    if (!d2a) {
      float cf = unkey(t2a | mb);
      int n = 0;
#pragma unroll
      for (int i = 0; i < 13; ++i) n += __popcll(__ballot(va[i] >= cf));
      if (n >= 261) { t2a |= mb; d2a = (n == 261); }
    }
    if (!d1b) {
      float cf = unkey(t1b | mb);
      int n = 0;
#pragma unroll
      for (int i = 0; i < 13; ++i) n += __popcll(__ballot(vb[i] >= cf));
      if (n >= 392) { t1b |= mb; d1b = (n == 392); }
    }
    if (!d2b) {
      float cf = unkey(t2b | mb);
      int n = 0;
#pragma unroll
      for (int i = 0; i < 13; ++i) n += __popcll(__ballot(vb[i] >= cf));
      if (n >= 261) { t2b |= mb; d2b = (n == 261); }
    }
    if (d1a & d2a & d1b & d2b) break;
  }
  const float T1a = unkey(t1a), T2a = unkey(t2a);
  const float T1b = unkey(t1b), T2b = unkey(t2b);

  // ---- fused exp + z + weights
  const float aw1 = aw1p[0], aw2 = aw2p[0];
  float ea[13], eb[13];
  float z1a = 0.f, z2a = 0.f, z1b = 0.f, z2b = 0.f;
#pragma unroll
  for (int i = 0; i < 13; ++i) {
    ea[i] = __expf(va[i] - mxa);
    eb[i] = __expf(vb[i] - mxb);
    if (va[i] >= T1a) z1a += ea[i];
    if (va[i] >= T2a) z2a += ea[i];
    if (vb[i] >= T1b) z1b += eb[i];
    if (vb[i] >= T2b) z2b += eb[i];
  }
#pragma unroll
  for (int off = 32; off; off >>= 1) {
    z1a += __shfl_xor(z1a, off, 64);
    z2a += __shfl_xor(z2a, off, 64);
    z1b += __shfl_xor(z1b, off, 64);
    z2b += __shfl_xor(z2b, off, 64);
  }
  const float a1a = aw1 / z1a, a2a = aw2 / z2a;
  const float a1b = aw1 / z1b, a2b = aw2 / z2b;
#pragma unroll
  for (int i = 0; i < 13; ++i) {
    int m = lane + i * 64;
    if (m < 784) {
      float wa = ea[i] * (((va[i] >= T1a) ? a1a : 0.f) + ((va[i] >= T2a) ? a2a : 0.f));
      sW[ra * 808 + m] = __float2bfloat16(wa);
      float wb = eb[i] * (((vb[i] >= T1b) ? a1b : 0.f) + ((vb[i] >= T2b) ? a2b : 0.f));
      sW[rb * 808 + m] = __float2bfloat16(wb);
    }
  }
  if (lane < 16) {
    sW[ra * 808 + 784 + lane] = __float2bfloat16(0.f);
    sW[rb * 808 + 784 + lane] = __float2bfloat16(0.f);
  }

  // ---- PV V-queue prefetch issued BEFORE the barrier
  const bf16* vbase = Vt + ((size_t)bh * 64 + w * 16 + fr) * 800;
  bf16x8 vq[4];
#pragma unroll
  for (int s = 0; s < 4; ++s)
    vq[s] = *reinterpret_cast<const bf16x8*>(vbase + s * 32 + ko);
  __syncthreads();

  // ---- PV via MFMA; two accumulator chains
  const bf16* wrow = sW + ((fr < 7) ? fr : 7) * 808;
  f32x4 acc0 = {0.f, 0.f, 0.f, 0.f}, acc1 = {0.f, 0.f, 0.f, 0.f};
#pragma unroll
  for (int ks = 0; ks < 25; ++ks) {
    const int s = ks & 3;
    bf16x8 a = *reinterpret_cast<const bf16x8*>(wrow + ks * 32 + ko);
    if (ks & 1)
      acc1 = __builtin_amdgcn_mfma_f32_16x16x32_bf16(a, vq[s], acc1, 0, 0, 0);
    else
      acc0 = __builtin_amdgcn_mfma_f32_16x16x32_bf16(a, vq[s], acc0, 0, 0, 0);
    if (ks + 4 < 25)
      vq[s] = *reinterpret_cast<const bf16x8*>(vbase + (ks + 4) * 32 + ko);
  }
  acc0 += acc1;
#pragma unroll
  for (int r = 0; r < 4; ++r) {
    int row = rh * 4 + r;
    if (row < 7) {
      float v = acc0[r];
      bf16 hi = __float2bfloat16(v);
      bf16 lo = __float2bfloat16(v - __bfloat162float(hi));
      size_t base = ((size_t)(b * 49 + r0 + row)) * 1024 + h * 64 + w * 16 + fr;
      aoutHL[base] = hi;
      aoutHL[base + 512] = lo;
    }
  }
}

// ---------------------------------------------------------------- launch
extern "C" void kernel_launch(void* const* d_in, const int* in_sizes, int n_in, void* d_out,
                              int out_size, void* d_ws, size_t ws_size, hipStream_t stream) {
  const float* x = (const float*)d_in[0];
  const float* y = (const float*)d_in[1];
  const float* Wq = (const float*)d_in[2];
  const float* Wkv = (const float*)d_in[3];
  const float* Wproj = (const float*)d_in[4];
  const float* bproj = (const float*)d_in[5];
  const float* gamma = (const float*)d_in[6];
  const float* beta = (const float*)d_in[7];
  const float* aw1 = (const float*)d_in[8];
  const float* aw2 = (const float*)d_in[9];
  float* out = (float*)d_out;

  char* w = (char*)d_ws;
  const size_t SZ = 51380224ull;    // 64*784*512*2 bytes
  const size_t SZV = 52428800ull;   // 64*8*64*800*2 bytes (V^T, padded stride 800)
  bf16* pooledT = (bf16*)(w);       // [50176][512]; LIVE through kv (read as A)
  bf16* Kb = (bf16*)(w + SZ);       // former yln slot (yln eliminated)
  bf16* Vt = (bf16*)(w + 2 * SZ);
  size_t off = 2 * SZ + SZV;
  bf16* xsTb = (bf16*)(w + off);    off += 3276800;   // [3200][512] bf16
  bf16* Qb = (bf16*)(w + off);      off += 3276800;   // [B,8,49,64] bf16
  bf16* aoutHL = (bf16*)(w + off);  off += 6553600;   // [3200][1024] bf16 (hi|lo)
  bf16* wkvT = (bf16*)(w + off);    off += 1048576;   // [1024][512] bf16 (gamma-folded)
  bf16* wqT = (bf16*)(w + off);     off += 524288;    // [512][512] bf16
  bf16* wpT = (bf16*)(w + off);     off += 524288;    // [512][512] bf16
  float* c1 = (float*)(w + off);    off += 4096;      // [1024] f32
  float* c2 = (float*)(w + off);    off += 4096;      // [1024] f32
  float2* stats = (float2*)(w + off); off += 401408;  // [50176] float2 (mu, rs)
  // peak ws use: ~171 MB

  prep_pool_kernel<<<dim3(7712), dim3(256), 0, stream>>>(Wkv, Wq, Wproj, x, y, gamma, beta, wkvT,
                                                         wqT, wpT, xsTb, Vt, pooledT, c1, c2);
  stats_q_kernel<<<dim3(12644), dim3(256), 0, stream>>>(pooledT, stats, xsTb, wqT, Qb);
  kv_mfma<<<dim3(8, 392), dim3(256), 18432, stream>>>(pooledT, wkvT, stats, c1, c2, Kb, Vt);
  attn_kernel<<<dim3(3584), dim3(256), 0, stream>>>(Qb, Kb, Vt, aw1, aw2, aoutHL);
  proj_mfma<<<dim3(4, 25), dim3(256), 0, stream>>>(aoutHL, wpT, bproj, out);
}

// Round 16
// 295.139 us; speedup vs baseline: 1.0442x; 1.0442x over previous
//
#include <hip/hip_runtime.h>
#include <hip/hip_bf16.h>

// MSCN fused pipeline, MI355X gfx950. Round 15: revert round-14 LN-fold
// (kv occupancy cliff: VGPR 116 -> 19% occ, +45us). This is the round-13
// best-measured configuration (295.2 us).
// B=64, C=512, H=W=7 (N=49), HY=WY=28 (N1=784), heads=8, d=64, SCALE=0.125
// kc1 = 784//2 = 392, kc2 = 784//3 = 261

typedef __hip_bfloat16 bf16;
using bf16x8 = __attribute__((ext_vector_type(8))) short;  // 8 bf16 = 4 VGPRs
using f32x4 = __attribute__((ext_vector_type(4))) float;

#define DI __device__ __forceinline__

DI unsigned short b2u(float f) {
  bf16 h = __float2bfloat16(f);
  return *reinterpret_cast<unsigned short*>(&h);
}
DI float u2f(short s) { return __uint_as_float(((unsigned int)(unsigned short)s) << 16); }

// inverse of the monotone float->uint key map (key = sign? ~u : u|0x80000000)
DI float unkey(unsigned int k) {
  unsigned int u = (k & 0x80000000u) ? (k & 0x7FFFFFFFu) : ~k;
  return __uint_as_float(u);
}

#define GLD_LDS16(g, l)                                                              \
  __builtin_amdgcn_global_load_lds((const __attribute__((address_space(1))) unsigned int*)(g), \
                                   (__attribute__((address_space(3))) unsigned int*)(l), 16, 0, 0)

// ---------------------------------------------------------------- prep + pool (merged)
// blocks [0,512): WkvT; [512,768): WqT; [768,1024): WprojT; [1024,1536): xstT
// (LDS-tiled coalesced); [1536,3584): vtpad; [3584,7680): pool (XCD-swizzled,
// wave-parallel scan).
__global__ __launch_bounds__(256) void prep_pool_kernel(
    const float* __restrict__ Wkv, const float* __restrict__ Wq, const float* __restrict__ Wproj,
    const float* __restrict__ x, const float* __restrict__ y, bf16* __restrict__ wkvT,
    bf16* __restrict__ wqT, bf16* __restrict__ wpT, bf16* __restrict__ xsTb,
    bf16* __restrict__ Vt, bf16* __restrict__ pooledT) {
  __shared__ __align__(16) unsigned char pMem[26912];  // union: t f32[32][33] / xt f32[64][51] / I f32[8][841]
  const int blk = blockIdx.x;
  const int tid = threadIdx.x;
  if (blk < 1024) {
    float(*t)[33] = reinterpret_cast<float(*)[33]>(pMem);
    const float* W;
    bf16* WT;
    int N, bx, by;
    if (blk < 512) { W = Wkv; WT = wkvT; N = 1024; bx = blk & 31; by = blk >> 5; }
    else if (blk < 768) { W = Wq; WT = wqT; N = 512; bx = (blk - 512) & 15; by = (blk - 512) >> 4; }
    else { W = Wproj; WT = wpT; N = 512; bx = (blk - 768) & 15; by = (blk - 768) >> 4; }
    const int n0 = bx * 32, k0 = by * 32;
    for (int i = tid; i < 1024; i += 256) {
      int kr = i >> 5, nc = i & 31;
      t[kr][nc] = W[(size_t)(k0 + kr) * N + n0 + nc];
    }
    __syncthreads();
    for (int i = tid; i < 1024; i += 256) {
      int nr = i >> 5, kc = i & 31;
      WT[(size_t)(n0 + nr) * 512 + k0 + kc] = __float2bfloat16(t[kc][nr]);
    }
  } else if (blk < 1536) {
    // xstT: block = (b, 64-c-group). Contiguous read, LDS transpose, coalesced write.
    float(*xt)[51] = reinterpret_cast<float(*)[51]>(pMem);  // [64][51] f32
    const int q2 = blk - 1024;           // [0,512)
    const int b = q2 >> 3, cg = q2 & 7;  // 64 b x 8 groups of 64 channels
    const float* xp = x + ((size_t)b * 512 + cg * 64) * 49;
    for (int i = tid; i < 3136; i += 256) {
      int cc = i / 49, r = i - cc * 49;
      xt[cc][r] = xp[i];
    }
    __syncthreads();
    for (int i = tid; i < 3136; i += 256) {
      int r = i >> 6, cc = i & 63;
      xsTb[((size_t)b * 49 + r) * 512 + cg * 64 + cc] = __float2bfloat16(xt[cc][r]);
    }
  } else if (blk < 3584) {
    int idx = (blk - 1536) * 256 + tid;  // 524288 total
    int row = idx >> 4, c = idx & 15;
    Vt[(size_t)row * 800 + 784 + c] = __float2bfloat16(0.f);
  } else {
    // pool: wave-parallel 2D prefix scan. XCD swizzle: all 64 cg-blocks of a
    // given b land on one XCD so partial 64B-line writes merge in its L2.
    float(*I)[841] = reinterpret_cast<float(*)[841]>(pMem);  // [plane][29*29], stride 29
    const int p = blk - 3584;  // [0,4096)
    const int wk = (p & 7) * 512 + (p >> 3);
    const int b = wk >> 6, cg = wk & 63;
    const float* srcb = y + ((size_t)b * 512 + cg * 8) * 784;
    bf16* drow = pooledT + ((size_t)b * 784) * 512 + cg * 8;
    for (int i = tid; i < 8 * 57; i += 256) {
      int q = i / 57, e = i - q * 57;
      I[q][(e < 29) ? e : (e - 28) * 29] = 0.f;
    }
    {
      const int w = tid >> 6, lane = tid & 63;
      const int hl = lane >> 5, c = lane & 31;
      const int pp = w * 2 + hl;
      if (c < 28) {
        const float* sp = srcb + (size_t)pp * 784;
        float run = 0.f;
        for (int r = 0; r < 28; ++r) {
          float v = sp[r * 28 + c];
#pragma unroll
          for (int d = 1; d < 28; d <<= 1) {
            float tt = __shfl_up(v, d, 32);
            if (c >= d) v += tt;
          }
          run += v;  // run = inclusive 2D prefix at (r, c)
          I[pp][(r + 1) * 29 + c + 1] = run;
        }
      }
    }
    __syncthreads();
    for (int j = tid; j < 784; j += 256) {
      int r = j / 28, c = j - (j / 28) * 28;
      int r0[3], r1[3], c0[3], c1[3];
#pragma unroll
      for (int pk = 1; pk <= 3; ++pk) {
        r0[pk - 1] = max(r - pk, 0) * 29;
        r1[pk - 1] = (min(r + pk, 27) + 1) * 29;
        c0[pk - 1] = max(c - pk, 0);
        c1[pk - 1] = min(c + pk, 27) + 1;
      }
      unsigned int u[4];
#pragma unroll
      for (int q = 0; q < 4; ++q) {
        float vv[2];
#pragma unroll
        for (int tt = 0; tt < 2; ++tt) {
          const float* Ip = I[q * 2 + tt];
          float acc = 0.f;
#pragma unroll
          for (int k = 0; k < 3; ++k) {
            float s = Ip[r1[k] + c1[k]] - Ip[r0[k] + c1[k]] - Ip[r1[k] + c0[k]] + Ip[r0[k] + c0[k]];
            acc += s * ((k == 0) ? (1.f / 9.f) : (k == 1) ? (1.f / 25.f) : (1.f / 49.f));
          }
          vv[tt] = acc;
        }
        u[q] = (unsigned int)b2u(vv[0]) | ((unsigned int)b2u(vv[1]) << 16);
      }
      *reinterpret_cast<uint4*>(drow + (size_t)j * 512) = make_uint4(u[0], u[1], u[2], u[3]);
    }
  }
}

// ---------------------------------------------------------------- lnrow + q_mfma (merged)
// blocks [0,100): q_mfma (bx=blk&3, by=blk>>2); [100,12644): row LayerNorm.
__global__ __launch_bounds__(256) void ln_q_kernel(const bf16* __restrict__ pooledT,
                                                   const float* __restrict__ gamma,
                                                   const float* __restrict__ beta,
                                                   bf16* __restrict__ yln,
                                                   const bf16* __restrict__ A,
                                                   const bf16* __restrict__ Bt,
                                                   bf16* __restrict__ Qb) {
  __shared__ __align__(16) bf16 As[128 * 32];
  __shared__ __align__(16) bf16 Bs[128 * 32];
  const int blk = blockIdx.x;
  const int tid = threadIdx.x;
  if (blk < 100) {
    const int lane = tid & 63;
    const int w = tid >> 6, wr = w >> 1, wc = w & 1;
    const int m0 = (blk >> 2) * 128, n0 = (blk & 3) * 128;
    f32x4 acc[4][4];
#pragma unroll
    for (int m = 0; m < 4; ++m)
#pragma unroll
      for (int n = 0; n < 4; ++n) acc[m][n] = f32x4{0.f, 0.f, 0.f, 0.f};
    const int s0 = tid, s1 = tid + 256;
    const bf16* Ag0 = A + (size_t)(m0 + (s0 >> 2)) * 512 + (s0 & 3) * 8;
    const bf16* Ag1 = A + (size_t)(m0 + (s1 >> 2)) * 512 + (s1 & 3) * 8;
    const bf16* Bg0 = Bt + (size_t)(n0 + (s0 >> 2)) * 512 + (s0 & 3) * 8;
    const bf16* Bg1 = Bt + (size_t)(n0 + (s1 >> 2)) * 512 + (s1 & 3) * 8;
    bf16* Al0 = As + s0 * 8;
    bf16* Al1 = As + s1 * 8;
    bf16* Bl0 = Bs + s0 * 8;
    bf16* Bl1 = Bs + s1 * 8;
    const int fr = lane & 15;
    const int ko = (lane >> 4) * 8;
    const int rh = lane >> 4;
    for (int k0 = 0; k0 < 512; k0 += 32) {
      GLD_LDS16(Ag0 + k0, Al0);
      GLD_LDS16(Ag1 + k0, Al1);
      GLD_LDS16(Bg0 + k0, Bl0);
      GLD_LDS16(Bg1 + k0, Bl1);
      __syncthreads();
      bf16x8 af[4], bfr[4];
#pragma unroll
      for (int m = 0; m < 4; ++m)
        af[m] = *reinterpret_cast<const bf16x8*>(As + (wr * 64 + m * 16 + fr) * 32 + ko);
#pragma unroll
      for (int n = 0; n < 4; ++n)
        bfr[n] = *reinterpret_cast<const bf16x8*>(Bs + (wc * 64 + n * 16 + fr) * 32 + ko);
#pragma unroll
      for (int m = 0; m < 4; ++m)
#pragma unroll
        for (int n = 0; n < 4; ++n)
          acc[m][n] = __builtin_amdgcn_mfma_f32_16x16x32_bf16(af[m], bfr[n], acc[m][n], 0, 0, 0);
      __syncthreads();
    }
#pragma unroll
    for (int m = 0; m < 4; ++m) {
#pragma unroll
      for (int n = 0; n < 4; ++n) {
        int col = n0 + wc * 64 + n * 16 + fr;  // 0..511: h=col>>6, d=col&63
        const size_t cbase = ((size_t)(col >> 6)) * (49 * 64) + (col & 63);
#pragma unroll
        for (int r = 0; r < 4; ++r) {
          int row = m0 + wr * 64 + m * 16 + rh * 4 + r;
          if (row < 3136) {
            int b = row / 49, rr = row - (row / 49) * 49;
            Qb[((size_t)b * 8) * (49 * 64) + cbase + (size_t)rr * 64] = __float2bfloat16(acc[m][n][r]);
          }
        }
      }
    }
  } else {
    const int row = (blk - 100) * 4 + (tid >> 6);
    const int lane = tid & 63;
    bf16x8 raw = *reinterpret_cast<const bf16x8*>(pooledT + (size_t)row * 512 + lane * 8);
    float v[8];
    float s = 0.f, s2 = 0.f;
#pragma unroll
    for (int j = 0; j < 8; ++j) {
      v[j] = u2f(raw[j]);
      s += v[j];
      s2 += v[j] * v[j];
    }
#pragma unroll
    for (int off = 32; off; off >>= 1) {
      s += __shfl_xor(s, off, 64);
      s2 += __shfl_xor(s2, off, 64);
    }
    float mu = s * (1.f / 512.f);
    float rs = rsqrtf(s2 * (1.f / 512.f) - mu * mu + 1e-5f);
    float4 g0 = *reinterpret_cast<const float4*>(gamma + lane * 8);
    float4 g1 = *reinterpret_cast<const float4*>(gamma + lane * 8 + 4);
    float4 e0 = *reinterpret_cast<const float4*>(beta + lane * 8);
    float4 e1 = *reinterpret_cast<const float4*>(beta + lane * 8 + 4);
    float gg[8] = {g0.x, g0.y, g0.z, g0.w, g1.x, g1.y, g1.z, g1.w};
    float bb[8] = {e0.x, e0.y, e0.z, e0.w, e1.x, e1.y, e1.z, e1.w};
    unsigned int u[4];
#pragma unroll
    for (int q = 0; q < 4; ++q) {
      float o0 = (v[2 * q] - mu) * rs * gg[2 * q] + bb[2 * q];
      float o1 = (v[2 * q + 1] - mu) * rs * gg[2 * q + 1] + bb[2 * q + 1];
      u[q] = (unsigned int)b2u(o0) | ((unsigned int)b2u(o1) << 16);
    }
    *reinterpret_cast<uint4*>(yln + (size_t)row * 512 + lane * 8) =
        make_uint4(u[0], u[1], u[2], u[3]);
  }
}

// ---------------------------------------------------------------- kv MFMA GEMM
__global__ __launch_bounds__(256) void kv_mfma(const bf16* __restrict__ A,
                                               const bf16* __restrict__ Bt,
                                               bf16* __restrict__ Kb, bf16* __restrict__ Vt) {
  extern __shared__ __align__(16) bf16 smem[];  // 18432 B dynamic
  bf16* As = smem;                              // [128*32]
  bf16* Bs = smem + 128 * 32;                   // [128*32]
  const int tid = threadIdx.x;
  const int lane = tid & 63;
  const int w = tid >> 6, wr = w >> 1, wc = w & 1;

  // XCD swizzle: XCD c handles y-tiles [c*49, c*49+49), all 8 x-tiles (A-tile L2 reuse)
  const int lin = blockIdx.y * 8 + blockIdx.x;
  const int c8 = lin & 7, j = lin >> 3;
  const int ex = j & 7, ey = c8 * 49 + (j >> 3);
  const int m0 = ey * 128, n0 = ex * 128;

  f32x4 acc[4][4];
#pragma unroll
  for (int m = 0; m < 4; ++m)
#pragma unroll
    for (int n = 0; n < 4; ++n) acc[m][n] = f32x4{0.f, 0.f, 0.f, 0.f};

  const int s0 = tid, s1 = tid + 256;  // 16B segments; seg s: row=s>>2, koff=(s&3)*8
  const bf16* Ag0 = A + (size_t)(m0 + (s0 >> 2)) * 512 + (s0 & 3) * 8;
  const bf16* Ag1 = A + (size_t)(m0 + (s1 >> 2)) * 512 + (s1 & 3) * 8;
  const bf16* Bg0 = Bt + (size_t)(n0 + (s0 >> 2)) * 512 + (s0 & 3) * 8;
  const bf16* Bg1 = Bt + (size_t)(n0 + (s1 >> 2)) * 512 + (s1 & 3) * 8;
  bf16* Al0 = As + s0 * 8;
  bf16* Al1 = As + s1 * 8;
  bf16* Bl0 = Bs + s0 * 8;
  bf16* Bl1 = Bs + s1 * 8;

  const int fr = lane & 15;        // fragment row/col within 16
  const int ko = (lane >> 4) * 8;  // k offset within 32
  const int rh = lane >> 4;

  for (int k0 = 0; k0 < 512; k0 += 32) {
    GLD_LDS16(Ag0 + k0, Al0);
    GLD_LDS16(Ag1 + k0, Al1);
    GLD_LDS16(Bg0 + k0, Bl0);
    GLD_LDS16(Bg1 + k0, Bl1);
    __syncthreads();  // vmcnt drained before barrier
    bf16x8 af[4], bfr[4];
#pragma unroll
    for (int m = 0; m < 4; ++m)
      af[m] = *reinterpret_cast<const bf16x8*>(As + (wr * 64 + m * 16 + fr) * 32 + ko);
#pragma unroll
    for (int n = 0; n < 4; ++n)
      bfr[n] = *reinterpret_cast<const bf16x8*>(Bs + (wc * 64 + n * 16 + fr) * 32 + ko);
#pragma unroll
    for (int m = 0; m < 4; ++m)
#pragma unroll
      for (int n = 0; n < 4; ++n)
        acc[m][n] = __builtin_amdgcn_mfma_f32_16x16x32_bf16(af[m], bfr[n], acc[m][n], 0, 0, 0);
    __syncthreads();
  }

  if (n0 < 512) {
    // ---- K epilogue: coalesced [b,h,m,d] writes
#pragma unroll
    for (int m = 0; m < 4; ++m) {
#pragma unroll
      for (int n = 0; n < 4; ++n) {
        int col = n0 + wc * 64 + n * 16 + fr;
        const size_t cbase = ((size_t)(col >> 6)) * (784 * 64) + (col & 63);
#pragma unroll
        for (int r = 0; r < 4; ++r) {
          int row = m0 + wr * 64 + m * 16 + rh * 4 + r;
          int b = row / 784, n1 = row - (row / 784) * 784;
          Kb[((size_t)b * 8) * (784 * 64) + cbase + (size_t)n1 * 64] = __float2bfloat16(acc[m][n][r]);
        }
      }
    }
  } else {
    // ---- V epilogue: LDS-staged transpose -> Vt [b*8+h][d][800]
    bf16* stage = smem;  // [128 cols][72 rows-padded]
#pragma unroll
    for (int p = 0; p < 2; ++p) {
      __syncthreads();
      if (wr == p) {
#pragma unroll
        for (int m = 0; m < 4; ++m) {
#pragma unroll
          for (int n = 0; n < 4; ++n) {
            int coll = wc * 64 + n * 16 + fr;
            int rowl = m * 16 + rh * 4;
            unsigned int u0 = (unsigned int)b2u(acc[m][n][0]) | ((unsigned int)b2u(acc[m][n][1]) << 16);
            unsigned int u1 = (unsigned int)b2u(acc[m][n][2]) | ((unsigned int)b2u(acc[m][n][3]) << 16);
            *reinterpret_cast<uint2*>(stage + coll * 72 + rowl) = make_uint2(u0, u1);
          }
        }
      }
      __syncthreads();
      const int rbase = m0 + p * 64;
      for (int i = tid; i < 1024; i += 256) {
        int cc = i >> 3, tc = i & 7;
        int colg = n0 + cc;  // >= 512
        int h = (colg >> 6) & 7, d = colg & 63;
        int rs = rbase + tc * 8;
        int b = rs / 784, n1 = rs - b * 784;
        bf16x8 val = *reinterpret_cast<const bf16x8*>(stage + cc * 72 + tc * 8);
        bf16* dst = Vt + (((size_t)b * 8 + h) * 64 + d) * 800 + n1;
        if (n1 <= 776) {
          *reinterpret_cast<bf16x8*>(dst) = val;
        } else {
#pragma unroll
          for (int jj = 0; jj < 8; ++jj) {
            int rr = rs + jj;
            int bb2 = rr / 784, nn1 = rr - bb2 * 784;
            bf16 hv;
            *reinterpret_cast<short*>(&hv) = val[jj];
            Vt[(((size_t)bb2 * 8 + h) * 64 + d) * 800 + nn1] = hv;
          }
        }
      }
    }
  }
}

// ---------------------------------------------------------------- proj MFMA GEMM
__global__ __launch_bounds__(256) void proj_mfma(const bf16* __restrict__ A,
                                                 const bf16* __restrict__ Bt,
                                                 const float* __restrict__ bias,
                                                 float* __restrict__ out) {
  __shared__ __align__(16) bf16 As[128 * 32];
  __shared__ __align__(16) bf16 Bs[128 * 32];
  const int tid = threadIdx.x;
  const int lane = tid & 63;
  const int w = tid >> 6, wr = w >> 1, wc = w & 1;
  const int m0 = blockIdx.y * 128, n0 = blockIdx.x * 128;

  f32x4 acc[4][4];
#pragma unroll
  for (int m = 0; m < 4; ++m)
#pragma unroll
    for (int n = 0; n < 4; ++n) acc[m][n] = f32x4{0.f, 0.f, 0.f, 0.f};

  const int s0 = tid, s1 = tid + 256;
  const bf16* Ag0 = A + (size_t)(m0 + (s0 >> 2)) * 1024 + (s0 & 3) * 8;
  const bf16* Ag1 = A + (size_t)(m0 + (s1 >> 2)) * 1024 + (s1 & 3) * 8;
  const bf16* Bg0 = Bt + (size_t)(n0 + (s0 >> 2)) * 512 + (s0 & 3) * 8;
  const bf16* Bg1 = Bt + (size_t)(n0 + (s1 >> 2)) * 512 + (s1 & 3) * 8;
  bf16* Al0 = As + s0 * 8;
  bf16* Al1 = As + s1 * 8;
  bf16* Bl0 = Bs + s0 * 8;
  bf16* Bl1 = Bs + s1 * 8;

  const int fr = lane & 15;
  const int ko = (lane >> 4) * 8;
  const int rh = lane >> 4;

  for (int k0 = 0; k0 < 1024; k0 += 32) {
    GLD_LDS16(Ag0 + k0, Al0);
    GLD_LDS16(Ag1 + k0, Al1);
    GLD_LDS16(Bg0 + (k0 & 511), Bl0);
    GLD_LDS16(Bg1 + (k0 & 511), Bl1);
    __syncthreads();
    bf16x8 af[4], bfr[4];
#pragma unroll
    for (int m = 0; m < 4; ++m)
      af[m] = *reinterpret_cast<const bf16x8*>(As + (wr * 64 + m * 16 + fr) * 32 + ko);
#pragma unroll
    for (int n = 0; n < 4; ++n)
      bfr[n] = *reinterpret_cast<const bf16x8*>(Bs + (wc * 64 + n * 16 + fr) * 32 + ko);
#pragma unroll
    for (int m = 0; m < 4; ++m)
#pragma unroll
      for (int n = 0; n < 4; ++n)
        acc[m][n] = __builtin_amdgcn_mfma_f32_16x16x32_bf16(af[m], bfr[n], acc[m][n], 0, 0, 0);
    __syncthreads();
  }

#pragma unroll
  for (int m = 0; m < 4; ++m) {
#pragma unroll
    for (int n = 0; n < 4; ++n) {
      int col = n0 + wc * 64 + n * 16 + fr;
      float bv = bias[col];
#pragma unroll
      for (int r = 0; r < 4; ++r) {
        int row = m0 + wr * 64 + m * 16 + rh * 4 + r;
        if (row < 3136) {
          int b = row / 49, rr = row - (row / 49) * 49;
          out[((size_t)b * 512 + col) * 49 + rr] = acc[m][n][r] + bv;
        }
      }
    }
  }
}

// ---------------------------------------------------------------- attention
// one block = (b,h, chunk of 7 q-rows). MFMA QK^T + MFMA PV with register
// load queues; 4 independent bisection chains; sW aliases sLog (stride 786
// f32 breaks the 4-way store conflict).
__global__ __launch_bounds__(256, 7) void attn_kernel(const bf16* __restrict__ Qb,
                                                      const bf16* __restrict__ K,
                                                      const bf16* __restrict__ Vt,
                                                      const float* __restrict__ aw1p,
                                                      const float* __restrict__ aw2p,
                                                      bf16* __restrict__ aoutHL) {
  // XCD swizzle: 3584 = 8*448; XCD c gets wk in [c*448,(c+1)*448) => bh in [c*64,(c+1)*64)
  const int lin = blockIdx.x;
  const int wk = (lin & 7) * 448 + (lin >> 3);
  const int bh = wk / 7;
  const int chunk = wk - bh * 7;
  const int b = bh >> 3, h = bh & 7;
  const int r0 = chunk * 7;
  const int tid = threadIdx.x;
  const int lane = tid & 63, w = tid >> 6;
  __shared__ __align__(16) unsigned char sMem[22008];  // union: sLog f32[7][786] / sW bf16[8][808]
  float* sLog = reinterpret_cast<float*>(sMem);
  bf16* sW = reinterpret_cast<bf16*>(sMem);
  // LDS ~22.0 KB -> 7 blocks/CU

  const int fr = lane & 15, ko = (lane >> 4) * 8, rh = lane >> 4;

  // ---- Q fragment: direct global load, row clamped (rows 7..15 garbage-OK)
  const bf16* Qp = Qb + ((size_t)bh * 49 + r0) * 64;
  const int qrow = (fr < 7) ? fr : 6;
  const bf16x8 aq0 = *reinterpret_cast<const bf16x8*>(Qp + qrow * 64 + ko);
  const bf16x8 aq1 = *reinterpret_cast<const bf16x8*>(Qp + qrow * 64 + 32 + ko);

  // ---- QK^T via MFMA with a 4-deep K register queue
  const bf16* Kp = K + (size_t)bh * (784 * 64);
  {
    const int rbase = rh * 4;
    const bf16* kbase = Kp + (size_t)fr * 64 + ko;
    bf16x8 kq0[4], kq1[4];
#pragma unroll
    for (int s = 0; s < 4; ++s) {
      int nt = w + s * 4;
      int ntc = nt < 49 ? nt : 48;
      const bf16* kr = kbase + (size_t)ntc * 1024;
      kq0[s] = *reinterpret_cast<const bf16x8*>(kr);
      kq1[s] = *reinterpret_cast<const bf16x8*>(kr + 32);
    }
#pragma unroll
    for (int i = 0; i < 13; ++i) {
      const int s = i & 3;
      const int nt = w + i * 4;
      if (nt < 49) {
        f32x4 acc = {0.f, 0.f, 0.f, 0.f};
        acc = __builtin_amdgcn_mfma_f32_16x16x32_bf16(aq0, kq0[s], acc, 0, 0, 0);
        acc = __builtin_amdgcn_mfma_f32_16x16x32_bf16(aq1, kq1[s], acc, 0, 0, 0);
#pragma unroll
        for (int r = 0; r < 4; ++r) {
          int row = rbase + r;
          if (row < 7) sLog[row * 786 + nt * 16 + fr] = acc[r] * 0.125f;
        }
      }
      const int ntn = w + (i + 4) * 4;
      if (ntn < 49) {
        const bf16* kr = kbase + (size_t)ntn * 1024;
        kq0[s] = *reinterpret_cast<const bf16x8*>(kr);
        kq1[s] = *reinterpret_cast<const bf16x8*>(kr + 32);
      }
    }
  }
  __syncthreads();

  // ---- load logits for this wave's two rows into registers
  const int ra = w;
  const int rb = (w + 4 < 7) ? (w + 4) : w;  // wave 3 duplicates its row (benign)
  float va[13], vb[13];
#pragma unroll
  for (int i = 0; i < 13; ++i) {
    int m = lane + i * 64;
    va[i] = (m < 784) ? sLog[ra * 786 + m] : -INFINITY;
    vb[i] = (m < 784) ? sLog[rb * 786 + m] : -INFINITY;
  }
  __syncthreads();  // sLog fully consumed; sW aliasing writes may begin

  // row max
  float mxa = va[0], mxb = vb[0];
#pragma unroll
  for (int i = 1; i < 13; ++i) {
    mxa = fmaxf(mxa, va[i]);
    mxb = fmaxf(mxb, vb[i]);
  }
#pragma unroll
  for (int off = 32; off; off >>= 1) {
    mxa = fmaxf(mxa, __shfl_xor(mxa, off, 64));
    mxb = fmaxf(mxb, __shfl_xor(mxb, off, 64));
  }

  // ---- 4 independent bisection chains in key space, compares in the float
  // domain. v >= unkey(cand) <=> key(v) >= cand (monotone bijection on finite
  // floats). Early exit when count==k is exact; ties fall to full bisection
  // -> >= kth semantics identical to reference.
  unsigned int t1a = 0u, t2a = 0u, t1b = 0u, t2b = 0u;
  bool d1a = false, d2a = false, d1b = false, d2b = false;
  for (int bit = 31; bit >= 0; --bit) {
    const unsigned int mb = 1u << bit;
    if (!d1a) {
      float cf = unkey(t1a | mb);
      int n = 0;
#pragma unroll
      for (int i = 0; i < 13; ++i) n += __popcll(__ballot(va[i] >= cf));
      if (n >= 392) { t1a |= mb; d1a = (n == 392); }
    }
    if (!d2a) {
      float cf = unkey(t2a | mb);
      int n = 0;
#pragma unroll
      for (int i = 0; i < 13; ++i) n += __popcll(__ballot(va[i] >= cf));
      if (n >= 261) { t2a |= mb; d2a = (n == 261); }
    }
    if (!d1b) {
      float cf = unkey(t1b | mb);
      int n = 0;
#pragma unroll
      for (int i = 0; i < 13; ++i) n += __popcll(__ballot(vb[i] >= cf));
      if (n >= 392) { t1b |= mb; d1b = (n == 392); }
    }
    if (!d2b) {
      float cf = unkey(t2b | mb);
      int n = 0;
#pragma unroll
      for (int i = 0; i < 13; ++i) n += __popcll(__ballot(vb[i] >= cf));
      if (n >= 261) { t2b |= mb; d2b = (n == 261); }
    }
    if (d1a & d2a & d1b & d2b) break;
  }
  const float T1a = unkey(t1a), T2a = unkey(t2a);
  const float T1b = unkey(t1b), T2b = unkey(t2b);

  // ---- fused exp + z + weights (e kept in registers)
  const float aw1 = aw1p[0], aw2 = aw2p[0];
  float ea[13], eb[13];
  float z1a = 0.f, z2a = 0.f, z1b = 0.f, z2b = 0.f;
#pragma unroll
  for (int i = 0; i < 13; ++i) {
    ea[i] = __expf(va[i] - mxa);  // pads: exp(-inf)=0
    eb[i] = __expf(vb[i] - mxb);
    if (va[i] >= T1a) z1a += ea[i];
    if (va[i] >= T2a) z2a += ea[i];
    if (vb[i] >= T1b) z1b += eb[i];
    if (vb[i] >= T2b) z2b += eb[i];
  }
#pragma unroll
  for (int off = 32; off; off >>= 1) {
    z1a += __shfl_xor(z1a, off, 64);
    z2a += __shfl_xor(z2a, off, 64);
    z1b += __shfl_xor(z1b, off, 64);
    z2b += __shfl_xor(z2b, off, 64);
  }
  const float a1a = aw1 / z1a, a2a = aw2 / z2a;
  const float a1b = aw1 / z1b, a2b = aw2 / z2b;
#pragma unroll
  for (int i = 0; i < 13; ++i) {
    int m = lane + i * 64;
    if (m < 784) {
      float wa = ea[i] * (((va[i] >= T1a) ? a1a : 0.f) + ((va[i] >= T2a) ? a2a : 0.f));
      sW[ra * 808 + m] = __float2bfloat16(wa);
      float wb = eb[i] * (((vb[i] >= T1b) ? a1b : 0.f) + ((vb[i] >= T2b) ? a2b : 0.f));
      sW[rb * 808 + m] = __float2bfloat16(wb);
    }
  }
  if (lane < 16) {
    sW[ra * 808 + 784 + lane] = __float2bfloat16(0.f);
    sW[rb * 808 + 784 + lane] = __float2bfloat16(0.f);
  }

  // ---- PV V-queue prefetch issued BEFORE the barrier (latency hides under it)
  const bf16* vbase = Vt + ((size_t)bh * 64 + w * 16 + fr) * 800;
  bf16x8 vq[4];
#pragma unroll
  for (int s = 0; s < 4; ++s)
    vq[s] = *reinterpret_cast<const bf16x8*>(vbase + s * 32 + ko);
  __syncthreads();

  // ---- PV via MFMA: out[16][64] = W[16][800] x V^T; wave w owns d-tile w*16..
  // A rows 7..15 clamped to row 7 (allocated; may be garbage -> C rows >=7
  // discarded). Two accumulator chains halve the dependent-MFMA latency.
  const bf16* wrow = sW + ((fr < 7) ? fr : 7) * 808;
  f32x4 acc0 = {0.f, 0.f, 0.f, 0.f}, acc1 = {0.f, 0.f, 0.f, 0.f};
#pragma unroll
  for (int ks = 0; ks < 25; ++ks) {
    const int s = ks & 3;
    bf16x8 a = *reinterpret_cast<const bf16x8*>(wrow + ks * 32 + ko);
    if (ks & 1)
      acc1 = __builtin_amdgcn_mfma_f32_16x16x32_bf16(a, vq[s], acc1, 0, 0, 0);
    else
      acc0 = __builtin_amdgcn_mfma_f32_16x16x32_bf16(a, vq[s], acc0, 0, 0, 0);
    if (ks + 4 < 25)
      vq[s] = *reinterpret_cast<const bf16x8*>(vbase + (ks + 4) * 32 + ko);
  }
  acc0 += acc1;
#pragma unroll
  for (int r = 0; r < 4; ++r) {
    int row = rh * 4 + r;
    if (row < 7) {
      float v = acc0[r];
      bf16 hi = __float2bfloat16(v);
      bf16 lo = __float2bfloat16(v - __bfloat162float(hi));
      size_t base = ((size_t)(b * 49 + r0 + row)) * 1024 + h * 64 + w * 16 + fr;
      aoutHL[base] = hi;
      aoutHL[base + 512] = lo;
    }
  }
}

// ---------------------------------------------------------------- launch
extern "C" void kernel_launch(void* const* d_in, const int* in_sizes, int n_in, void* d_out,
                              int out_size, void* d_ws, size_t ws_size, hipStream_t stream) {
  const float* x = (const float*)d_in[0];
  const float* y = (const float*)d_in[1];
  const float* Wq = (const float*)d_in[2];
  const float* Wkv = (const float*)d_in[3];
  const float* Wproj = (const float*)d_in[4];
  const float* bproj = (const float*)d_in[5];
  const float* gamma = (const float*)d_in[6];
  const float* beta = (const float*)d_in[7];
  const float* aw1 = (const float*)d_in[8];
  const float* aw2 = (const float*)d_in[9];
  float* out = (float*)d_out;

  char* w = (char*)d_ws;
  const size_t SZ = 51380224ull;    // 64*784*512*2 bytes
  const size_t SZV = 52428800ull;   // 64*8*64*800*2 bytes (V^T, padded stride 800)
  bf16* pooledT = (bf16*)(w);       // [50176][512]; dead after lnrow
  bf16* yln = (bf16*)(w + SZ);      // [50176][512]; dead after kv gemm
  bf16* Kb = (bf16*)(w);            // reuses pooledT slot (after lnrow)
  bf16* Vt = (bf16*)(w + 2 * SZ);
  size_t off = 2 * SZ + SZV;
  bf16* xsTb = (bf16*)(w + off);    off += 3276800;   // [3200][512] bf16 (64 pad rows)
  bf16* Qb = (bf16*)(w + off);      off += 3276800;   // [B,8,49,64] bf16
  bf16* aoutHL = (bf16*)(w + off);  off += 6553600;   // [3200][1024] bf16 (hi|lo)
  bf16* wkvT = (bf16*)(w + off);    off += 1048576;   // [1024][512] bf16
  bf16* wqT = (bf16*)(w + off);     off += 524288;    // [512][512] bf16
  bf16* wpT = (bf16*)(w + off);     off += 524288;    // [512][512] bf16
  // peak ws use: ~170.4 MB

  prep_pool_kernel<<<dim3(7680), dim3(256), 0, stream>>>(Wkv, Wq, Wproj, x, y, wkvT, wqT, wpT,
                                                         xsTb, Vt, pooledT);
  ln_q_kernel<<<dim3(12644), dim3(256), 0, stream>>>(pooledT, gamma, beta, yln, xsTb, wqT, Qb);
  kv_mfma<<<dim3(8, 392), dim3(256), 18432, stream>>>(yln, wkvT, Kb, Vt);
  attn_kernel<<<dim3(3584), dim3(256), 0, stream>>>(Qb, Kb, Vt, aw1, aw2, aoutHL);
  proj_mfma<<<dim3(4, 25), dim3(256), 0, stream>>>(aoutHL, wpT, bproj, out);
}